// Round 24
// baseline (90.706 us; speedup 1.0000x reference)
//
#include <hip/hip_runtime.h>
#include <hip/hip_fp16.h>

#define NNODES 100000
#define DIM 64
#define TILE 128
#define NTILES ((NNODES + TILE - 1) / TILE)   // 782
#define NTPAD 784
#define TS_STRIDE 785                          // per-block tileStart entries (784 + total)
#define CAP 2560        // per-tile: mean padded 2048, +10 sigma
#define EPT 16
#define BIN_THREADS 512
#define BIN_CHUNK (BIN_THREADS * EPT)          // 8192 edges per block
#define NPAIR 4                                 // feature-pair tables (16 feats each)
#define SN_THREADS 512

// Block-contiguous counting sort: each block sorts its 8192 edges by tile into
// its OWN 32KB region (writes stay L2-resident -> full-line evictions) and
// publishes per-block tileStart tables. NO global atomics anywhere.
__global__ __launch_bounds__(BIN_THREADS) void bin_kernel(
        const int* __restrict__ src, const int* __restrict__ dst,
        int* __restrict__ blockD, unsigned char* __restrict__ blockSb,
        unsigned short* __restrict__ tsD, unsigned short* __restrict__ tsS, int E) {
    __shared__ int histD[NTPAD], histS[NTPAD];
    __shared__ int baseD[TS_STRIDE], baseS[TS_STRIDE];
    __shared__ int wsumD[8], wsumS[8];
    int dv[EPT], sv[EPT];
    unsigned short rD[EPT], rS[EPT];
    int tid = threadIdx.x;
    int blk = blockIdx.x;
    for (int t = tid; t < NTPAD; t += BIN_THREADS) { histD[t] = 0; histS[t] = 0; }
    __syncthreads();
    int base = blk * BIN_CHUNK;
    #pragma unroll
    for (int i = 0; i < EPT; i++) {
        int idx = base + i * BIN_THREADS + tid;
        if (idx < E) {
            int d = dst[idx];
            int s = src[idx];
            dv[i] = d;
            sv[i] = s;
            rD[i] = (unsigned short)atomicAdd(&histD[d >> 7], 1);
            rS[i] = (unsigned short)atomicAdd(&histS[s >> 7], 1);
        }
    }
    __syncthreads();
    // exclusive scan of histD/histS (784 elems, 2 per thread) -> baseD/baseS
    {
        int i0 = 2 * tid, i1 = 2 * tid + 1;
        int aD = (i0 < NTPAD) ? histD[i0] : 0;
        int bD = (i1 < NTPAD) ? histD[i1] : 0;
        int aS = (i0 < NTPAD) ? histS[i0] : 0;
        int bS = (i1 < NTPAD) ? histS[i1] : 0;
        int vD = aD + bD, vS = aS + bS;
        int lane = tid & 63, w = tid >> 6;
        int xD = vD, xS = vS;
        #pragma unroll
        for (int off = 1; off < 64; off <<= 1) {
            int yD = __shfl_up(xD, off, 64);
            int yS = __shfl_up(xS, off, 64);
            if (lane >= off) { xD += yD; xS += yS; }
        }
        if (lane == 63) { wsumD[w] = xD; wsumS[w] = xS; }
        __syncthreads();
        if (tid == 0) {
            int runD = 0, runS = 0;
            #pragma unroll
            for (int k = 0; k < 8; k++) {
                int tD = wsumD[k]; wsumD[k] = runD; runD += tD;
                int tS = wsumS[k]; wsumS[k] = runS; runS += tS;
            }
            baseD[NTPAD] = runD;
            baseS[NTPAD] = runS;
        }
        __syncthreads();
        int exD = xD - vD + wsumD[w];
        int exS = xS - vS + wsumS[w];
        if (i0 < NTPAD) { baseD[i0] = exD; baseS[i0] = exS; }
        if (i1 < NTPAD) { baseD[i1] = exD + aD; baseS[i1] = exS + aS; }
    }
    __syncthreads();
    // publish tileStart tables (coalesced ushort writes)
    for (int t = tid; t <= NTPAD; t += BIN_THREADS) {
        tsD[(size_t)blk * TS_STRIDE + t] = (unsigned short)baseD[t];
        tsS[(size_t)blk * TS_STRIDE + t] = (unsigned short)baseS[t];
    }
    // scatter into own 32KB / 8KB regions (L2-resident windows)
    #pragma unroll
    for (int i = 0; i < EPT; i++) {
        int idx = base + i * BIN_THREADS + tid;
        if (idx < E) {
            int d = dv[i];
            int s = sv[i];
            int pD = baseD[d >> 7] + (int)rD[i];
            int pS = baseS[s >> 7] + (int)rS[i];
            blockD[((size_t)blk << 13) + pD] = ((unsigned)(d & 127) << 17) | (unsigned)s;
            blockSb[((size_t)blk << 13) + pS] = (unsigned char)(s & 127);
        }
    }
}

// Fused per-tile kernel (782 blocks, 512 threads).
// Phase A: gather tile's src-bytes from per-block segments -> histogram ->
//          norms -> convert tile's emb rows into 4 fp16 pair-tables.
// Phase B: gather tile's dst-edges into LDS (deterministic scan order) ->
//          counting sort -> sortedD runs padded to 8 + sentinel; offs/deg.
__global__ __launch_bounds__(SN_THREADS) void sortnorm_kernel(
        const int* __restrict__ blockD, const unsigned char* __restrict__ blockSb,
        const unsigned short* __restrict__ tsD, const unsigned short* __restrict__ tsS,
        int nblk, const float* __restrict__ emb, __half* __restrict__ embp,
        int* __restrict__ sortedD, int* __restrict__ offs, int* __restrict__ deg) {
    __shared__ int cnt[TILE];
    __shared__ int cur[TILE];
    __shared__ float norm_s[TILE];
    __shared__ int wsum[8];
    __shared__ int gtot_s, tot_s;
    __shared__ int ebuf[CAP];
    int t = blockIdx.x, tid = threadIdx.x;
    if (tid < TILE) cnt[tid] = 0;
    __syncthreads();
    // Phase A: src histogram from per-block byte segments
    if (tid < nblk) {
        const unsigned short* ts = tsS + (size_t)tid * TS_STRIDE;
        int s0 = ts[t], s1 = ts[t + 1];
        const unsigned char* seg = blockSb + ((size_t)tid << 13);
        for (int j = s0; j < s1; j++)
            atomicAdd(&cnt[seg[j]], 1);
    }
    __syncthreads();
    if (tid < TILE)
        norm_s[tid] = rsqrtf(fmaxf((float)cnt[tid], 1.0f));
    __syncthreads();
    // convert this tile's rows into the 4 pair-tables (512 chunks: 1 round)
    {
        int nrows = min(TILE, NNODES - t * TILE);
        int chunks = nrows * NPAIR;
        size_t ebase = (size_t)t * TILE * DIM;
        for (int i = tid; i < chunks; i += SN_THREADS) {
            int row = i >> 2;
            int pair = i & 3;
            const float* ep = emb + ebase + (size_t)row * DIM + pair * 16;
            float w = norm_s[row];
            float4 a = *(const float4*)(ep);
            float4 b = *(const float4*)(ep + 4);
            float4 c = *(const float4*)(ep + 8);
            float4 d4 = *(const float4*)(ep + 12);
            int gnode = t * TILE + row;
            __half2* o = (__half2*)(embp + ((size_t)pair * (NNODES + 1) + gnode) * 16);
            o[0] = __floats2half2_rn(a.x * w, a.y * w);
            o[1] = __floats2half2_rn(a.z * w, a.w * w);
            o[2] = __floats2half2_rn(b.x * w, b.y * w);
            o[3] = __floats2half2_rn(b.z * w, b.w * w);
            o[4] = __floats2half2_rn(c.x * w, c.y * w);
            o[5] = __floats2half2_rn(c.z * w, c.w * w);
            o[6] = __floats2half2_rn(d4.x * w, d4.y * w);
            o[7] = __floats2half2_rn(d4.z * w, d4.w * w);
        }
        if (t * TILE + tid == NNODES) {   // zero sentinel rows in all pair-tables
            __half2 z = __floats2half2_rn(0.0f, 0.0f);
            #pragma unroll
            for (int p = 0; p < NPAIR; p++) {
                __half2* o = (__half2*)(embp + ((size_t)p * (NNODES + 1) + NNODES) * 16);
                #pragma unroll
                for (int k = 0; k < 8; k++) o[k] = z;
            }
        }
    }
    __syncthreads();
    // Phase B: gather dst-edge segments into ebuf (deterministic block-major order)
    int n = 0, s0 = 0;
    if (tid < nblk) {
        const unsigned short* ts = tsD + (size_t)tid * TS_STRIDE;
        s0 = ts[t];
        n = ts[t + 1] - s0;
    }
    {
        int lane = tid & 63, w = tid >> 6;
        int x = n;
        #pragma unroll
        for (int off = 1; off < 64; off <<= 1) {
            int y = __shfl_up(x, off, 64);
            if (lane >= off) x += y;
        }
        if (lane == 63) wsum[w] = x;
        __syncthreads();
        if (tid == 0) {
            int run = 0;
            #pragma unroll
            for (int k = 0; k < 8; k++) { int tt = wsum[k]; wsum[k] = run; run += tt; }
            gtot_s = run;
        }
        __syncthreads();
        int pos = x - n + wsum[w];
        if (tid < nblk) {
            const int* sp = blockD + ((size_t)tid << 13) + s0;
            for (int k = 0; k < n; k++) {
                int p = pos + k;
                if (p < CAP) ebuf[p] = sp[k];
            }
        }
    }
    __syncthreads();
    int len = min(gtot_s, CAP);
    if (tid < TILE) cnt[tid] = 0;
    __syncthreads();
    for (int j = tid; j < len; j += SN_THREADS)
        atomicAdd(&cnt[((unsigned)ebuf[j]) >> 17], 1);
    __syncthreads();
    int v = 0, ex = 0;
    if (tid < TILE) {
        v = cnt[tid];
        int vpad = (v + 7) & ~7;              // pad runs to multiples of 8 ints
        int lane = tid & 63, w = tid >> 6;    // w in {0,1}
        int x = vpad;
        #pragma unroll
        for (int off = 1; off < 64; off <<= 1) {
            int y = __shfl_up(x, off, 64);
            if (lane >= off) x += y;
        }
        if (lane == 63) wsum[w] = x;
        __syncthreads();
        int add = (w == 1) ? wsum[0] : 0;
        ex = x - vpad + add;                  // exclusive prefix of padded counts
        cur[tid] = ex;
        if (tid == TILE - 1) tot_s = ex + vpad;
    } else {
        __syncthreads();
    }
    __syncthreads();
    for (int j = tid; j < len; j += SN_THREADS) {
        unsigned int p = (unsigned)ebuf[j];
        int dl = p >> 17;
        int pos = atomicAdd(&cur[dl], 1);
        if (pos < CAP) sortedD[(size_t)t * CAP + pos] = (int)(p & 0x1FFFF);
    }
    __syncthreads();
    // per-node pad fill and tile slack fill with zero-row sentinel
    if (tid < TILE) {
        int vpad = (v + 7) & ~7;
        int pe = ex + vpad;
        for (int p = cur[tid]; p < pe && p < CAP; p++) sortedD[(size_t)t * CAP + p] = NNODES;
    }
    for (int k = tot_s + tid; k < CAP; k += SN_THREADS) sortedD[(size_t)t * CAP + k] = NNODES;
    int node = t * TILE + tid;
    if (tid < TILE && node < NNODES) {
        offs[node] = t * CAP + ex;
        deg[node] = v;
    }
}

// Feature-partitioned aggregate: block = (node-group of 32, pair), pair = bid&3.
// Round-robin dispatch maps all blocks of pair p onto XCDs {p, p+4} -> each
// XCD's random gathers hit ONE L2-resident 3.2MB pair-table. (Unchanged.)
__global__ __launch_bounds__(256) void agg6_kernel(
        const __half* __restrict__ embp, const int* __restrict__ offs,
        const int* __restrict__ deg, const int* __restrict__ sortedD,
        float* __restrict__ out) {
    int bid = blockIdx.x;
    int pair = bid & 3;
    int g = bid >> 2;
    int wid = threadIdx.x >> 6;
    int lane = threadIdx.x & 63;
    int nodesub = lane >> 3;
    int slot = (lane >> 1) & 3;
    int hl = lane & 1;
    int node = g * 32 + wid * 8 + nodesub;
    if (node >= NNODES) return;
    int m = deg[node];
    int mp = (m + 7) & ~7;
    const int* run = sortedD + offs[node];
    const __half* tbl = embp + (size_t)pair * (NNODES + 1) * 16;
    __half2 hz = __floats2half2_rn(0.0f, 0.0f);
    __half2 h0 = hz, h1 = hz, h2 = hz, h3 = hz;
    for (int j = 0; j < mp; j += 8) {
        int i0 = run[j + slot];
        int i1 = run[j + 4 + slot];
        float4 v0 = *(const float4*)(tbl + ((size_t)i0 << 4) + (hl << 3));
        float4 v1 = *(const float4*)(tbl + ((size_t)i1 << 4) + (hl << 3));
        const __half2* p0 = (const __half2*)&v0;
        const __half2* p1 = (const __half2*)&v1;
        h0 = __hadd2(h0, p0[0]); h1 = __hadd2(h1, p0[1]);
        h2 = __hadd2(h2, p0[2]); h3 = __hadd2(h3, p0[3]);
        h0 = __hadd2(h0, p1[0]); h1 = __hadd2(h1, p1[1]);
        h2 = __hadd2(h2, p1[2]); h3 = __hadd2(h3, p1[3]);
    }
    float2 f0 = __half22float2(h0);
    float2 f1 = __half22float2(h1);
    float2 f2 = __half22float2(h2);
    float2 f3 = __half22float2(h3);
    float a0 = f0.x, a1 = f0.y, a2 = f1.x, a3 = f1.y;
    float a4 = f2.x, a5 = f2.y, a6 = f3.x, a7 = f3.y;
    #pragma unroll
    for (int off = 2; off <= 4; off <<= 1) {
        a0 += __shfl_xor(a0, off);
        a1 += __shfl_xor(a1, off);
        a2 += __shfl_xor(a2, off);
        a3 += __shfl_xor(a3, off);
        a4 += __shfl_xor(a4, off);
        a5 += __shfl_xor(a5, off);
        a6 += __shfl_xor(a6, off);
        a7 += __shfl_xor(a7, off);
    }
    float dn = rsqrtf(fmaxf((float)m, 1.0f));
    if (slot == 0) {
        float* op = out + ((size_t)node << 6) + (pair << 4) + (hl << 3);
        *(float4*)(op) = make_float4(a0 * dn, a1 * dn, a2 * dn, a3 * dn);
        *(float4*)(op + 4) = make_float4(a4 * dn, a5 * dn, a6 * dn, a7 * dn);
    }
}

extern "C" void kernel_launch(void* const* d_in, const int* in_sizes, int n_in,
                              void* d_out, int out_size, void* d_ws, size_t ws_size,
                              hipStream_t stream) {
    const float* emb = (const float*)d_in[0];
    const int* src = (const int*)d_in[1];
    const int* dst = (const int*)d_in[2];
    int E = in_sizes[1];
    float* out = (float*)d_out;

    int nblk = (E + BIN_CHUNK - 1) / BIN_CHUNK;                   // 153 for E=1.25M
    char* p = (char*)d_ws;
    auto align16 = [](char* q) { return (char*)(((uintptr_t)q + 15) & ~(uintptr_t)15); };

    int* blockD = (int*)p;                 p += (size_t)nblk * BIN_CHUNK * 4;
    unsigned char* blockSb = (unsigned char*)p;  p += (size_t)nblk * BIN_CHUNK;
    p = align16(p);
    unsigned short* tsD = (unsigned short*)p;    p += (size_t)nblk * TS_STRIDE * 2;
    p = align16(p);
    unsigned short* tsS = (unsigned short*)p;    p += (size_t)nblk * TS_STRIDE * 2;
    p = align16(p);
    int* sortedD = (int*)p;                p += (size_t)NTILES * CAP * 4;
    int* offs = (int*)p;                   p += (size_t)NNODES * 4;
    int* deg = (int*)p;                    p += (size_t)NNODES * 4;
    p = align16(p);
    __half* embp = (__half*)p;             // [NPAIR*(N+1)*16]

    bin_kernel<<<nblk, BIN_THREADS, 0, stream>>>(src, dst, blockD, blockSb, tsD, tsS, E);

    sortnorm_kernel<<<NTILES, SN_THREADS, 0, stream>>>(blockD, blockSb, tsD, tsS, nblk,
                                                       emb, embp, sortedD, offs, deg);

    int ngroups = (NNODES + 31) / 32;         // 3125
    agg6_kernel<<<ngroups * NPAIR, 256, 0, stream>>>(embp, offs, deg, sortedD, out);
}

// Round 25
// 88.048 us; speedup vs baseline: 1.0302x; 1.0302x over previous
//
#include <hip/hip_runtime.h>
#include <hip/hip_fp16.h>

#define NNODES 100000
#define DIM 64
#define TILE 128
#define NTILES ((NNODES + TILE - 1) / TILE)   // 782
#define NTPAD 784
#define CAP 2560        // per-tile: mean padded 2048, +10 sigma
#define EPT 16
#define BIN_THREADS 512
#define BIN_CHUNK (BIN_THREADS * EPT)          // 8192 edges per block -> 153 blocks
#define NPAIR 4                                 // feature-pair tables (16 feats each)
#define SN_THREADS 512

// Zero gcurD+gcurS (2*NTPAD ints).
__global__ void init_kernel(int* __restrict__ gcur) {
    int i = blockIdx.x * blockDim.x + threadIdx.x;
    if (i < 2 * NTPAD) gcur[i] = 0;
}

// Counting-sort edges by dst-tile (and src ids by src-tile) with LDS ranking.
// Global atomics: one per (block, tile) only. S-side stores BYTES (s&127).
// Per-edge state (d, s, ranks) is held in REGISTERS across the two passes.
__global__ __launch_bounds__(BIN_THREADS) void bin_kernel(
        const int* __restrict__ src, const int* __restrict__ dst,
        int* __restrict__ gcurD, int* __restrict__ gcurS,
        unsigned int* __restrict__ binnedD, unsigned char* __restrict__ binnedSb, int E) {
    __shared__ int histD[NTPAD], histS[NTPAD], baseD[NTPAD], baseS[NTPAD];
    int dv[EPT], sv[EPT];
    unsigned short rD[EPT], rS[EPT];
    int tid = threadIdx.x;
    for (int t = tid; t < NTPAD; t += BIN_THREADS) { histD[t] = 0; histS[t] = 0; }
    __syncthreads();
    int base = blockIdx.x * BIN_CHUNK;
    #pragma unroll
    for (int i = 0; i < EPT; i++) {
        int idx = base + i * BIN_THREADS + tid;
        if (idx < E) {
            int d = dst[idx];
            int s = src[idx];
            dv[i] = d;
            sv[i] = s;
            rD[i] = (unsigned short)atomicAdd(&histD[d >> 7], 1);
            rS[i] = (unsigned short)atomicAdd(&histS[s >> 7], 1);
        }
    }
    __syncthreads();
    for (int t = tid; t < NTPAD; t += BIN_THREADS) {
        int h = histD[t];
        baseD[t] = h ? atomicAdd(&gcurD[t], h) : 0;
        h = histS[t];
        baseS[t] = h ? atomicAdd(&gcurS[t], h) : 0;
    }
    __syncthreads();
    #pragma unroll
    for (int i = 0; i < EPT; i++) {
        int idx = base + i * BIN_THREADS + tid;
        if (idx < E) {
            int d = dv[i];
            int s = sv[i];
            int tD = d >> 7, tS = s >> 7;
            int pD = baseD[tD] + (int)rD[i];
            int pS = baseS[tS] + (int)rS[i];
            if (pD < CAP) binnedD[(size_t)tD * CAP + pD] = ((unsigned)(d & 127) << 17) | (unsigned)s;
            if (pS < CAP) binnedSb[(size_t)tS * CAP + pS] = (unsigned char)(s & 127);
        }
    }
}

// Fused per-tile kernel, 512 threads.
// Phase A: src byte-histogram -> norms (LDS) -> convert tile's emb rows into 4
//          pre-normalized fp16 pair-tables embp[pair][node][16].
// Phase B: LDS counting sort of dst edges -> per-node runs padded to 8 ints,
//          pads/slack filled with sentinel NNODES (zero row).
__global__ __launch_bounds__(SN_THREADS) void sortnorm_kernel(
        const int* __restrict__ gcurS, const unsigned char* __restrict__ binnedSb,
        const int* __restrict__ gcurD, const unsigned int* __restrict__ binnedD,
        const float* __restrict__ emb, __half* __restrict__ embp,
        int* __restrict__ sortedD, int* __restrict__ offs, int* __restrict__ deg) {
    __shared__ int cnt[TILE];
    __shared__ int cur[TILE];
    __shared__ float norm_s[TILE];
    __shared__ int wsum[2];
    __shared__ int tot_s;
    int t = blockIdx.x, tid = threadIdx.x;
    if (tid < TILE) cnt[tid] = 0;
    __syncthreads();
    {
        int lenS = min(gcurS[t], CAP);
        const unsigned char* segS = binnedSb + (size_t)t * CAP;
        for (int j = tid; j < lenS; j += SN_THREADS)
            atomicAdd(&cnt[segS[j]], 1);
    }
    __syncthreads();
    if (tid < TILE)
        norm_s[tid] = rsqrtf(fmaxf((float)cnt[tid], 1.0f));
    __syncthreads();
    // convert this tile's rows into the 4 pair-tables (128*4 = 512 chunks: 1 round)
    {
        int nrows = min(TILE, NNODES - t * TILE);
        int chunks = nrows * NPAIR;
        size_t ebase = (size_t)t * TILE * DIM;
        for (int i = tid; i < chunks; i += SN_THREADS) {
            int row = i >> 2;
            int pair = i & 3;
            const float* ep = emb + ebase + (size_t)row * DIM + pair * 16;
            float w = norm_s[row];
            float4 a = *(const float4*)(ep);
            float4 b = *(const float4*)(ep + 4);
            float4 c = *(const float4*)(ep + 8);
            float4 d4 = *(const float4*)(ep + 12);
            int gnode = t * TILE + row;
            __half2* o = (__half2*)(embp + ((size_t)pair * (NNODES + 1) + gnode) * 16);
            o[0] = __floats2half2_rn(a.x * w, a.y * w);
            o[1] = __floats2half2_rn(a.z * w, a.w * w);
            o[2] = __floats2half2_rn(b.x * w, b.y * w);
            o[3] = __floats2half2_rn(b.z * w, b.w * w);
            o[4] = __floats2half2_rn(c.x * w, c.y * w);
            o[5] = __floats2half2_rn(c.z * w, c.w * w);
            o[6] = __floats2half2_rn(d4.x * w, d4.y * w);
            o[7] = __floats2half2_rn(d4.z * w, d4.w * w);
        }
        if (t * TILE + tid == NNODES) {   // zero sentinel rows in all pair-tables
            __half2 z = __floats2half2_rn(0.0f, 0.0f);
            #pragma unroll
            for (int p = 0; p < NPAIR; p++) {
                __half2* o = (__half2*)(embp + ((size_t)p * (NNODES + 1) + NNODES) * 16);
                #pragma unroll
                for (int k = 0; k < 8; k++) o[k] = z;
            }
        }
    }
    __syncthreads();
    if (tid < TILE) cnt[tid] = 0;
    __syncthreads();
    int len = min(gcurD[t], CAP);
    const unsigned int* seg = binnedD + (size_t)t * CAP;
    for (int j = tid; j < len; j += SN_THREADS)
        atomicAdd(&cnt[seg[j] >> 17], 1);
    __syncthreads();
    int v = 0, ex = 0;
    if (tid < TILE) {
        v = cnt[tid];
        int vpad = (v + 7) & ~7;              // pad runs to multiples of 8 ints
        int lane = tid & 63, w = tid >> 6;    // w in {0,1}
        int x = vpad;
        #pragma unroll
        for (int off = 1; off < 64; off <<= 1) {
            int y = __shfl_up(x, off, 64);
            if (lane >= off) x += y;
        }
        if (lane == 63) wsum[w] = x;
        __syncthreads();
        int add = (w == 1) ? wsum[0] : 0;
        ex = x - vpad + add;                  // exclusive prefix of padded counts
        cur[tid] = ex;
        if (tid == TILE - 1) tot_s = ex + vpad;
    } else {
        __syncthreads();
    }
    __syncthreads();
    for (int j = tid; j < len; j += SN_THREADS) {
        unsigned int p = seg[j];
        int dl = p >> 17;
        int pos = atomicAdd(&cur[dl], 1);
        if (pos < CAP) sortedD[(size_t)t * CAP + pos] = (int)(p & 0x1FFFF);
    }
    __syncthreads();
    // per-node pad fill and tile slack fill with zero-row sentinel
    if (tid < TILE) {
        int vpad = (v + 7) & ~7;
        int pe = ex + vpad;
        for (int p = cur[tid]; p < pe && p < CAP; p++) sortedD[(size_t)t * CAP + p] = NNODES;
    }
    for (int k = tot_s + tid; k < CAP; k += SN_THREADS) sortedD[(size_t)t * CAP + k] = NNODES;
    int node = t * TILE + tid;
    if (tid < TILE && node < NNODES) {
        offs[node] = t * CAP + ex;
        deg[node] = v;
    }
}

// Feature-partitioned aggregate: block = (node-group of 32, pair), pair = bid&3.
// Round-robin dispatch maps all blocks of pair p onto XCDs {p, p+4} -> each
// XCD's random gathers hit ONE L2-resident 3.2MB pair-table.
// Wave: 8 nodes x 4 slots x 2 half-rows; 16B gathers; fp16 accum; 2-level shfl.
__global__ __launch_bounds__(256) void agg6_kernel(
        const __half* __restrict__ embp, const int* __restrict__ offs,
        const int* __restrict__ deg, const int* __restrict__ sortedD,
        float* __restrict__ out) {
    int bid = blockIdx.x;
    int pair = bid & 3;
    int g = bid >> 2;
    int wid = threadIdx.x >> 6;
    int lane = threadIdx.x & 63;
    int nodesub = lane >> 3;
    int slot = (lane >> 1) & 3;
    int hl = lane & 1;
    int node = g * 32 + wid * 8 + nodesub;
    if (node >= NNODES) return;
    int m = deg[node];
    int mp = (m + 7) & ~7;
    const int* run = sortedD + offs[node];
    const __half* tbl = embp + (size_t)pair * (NNODES + 1) * 16;
    __half2 hz = __floats2half2_rn(0.0f, 0.0f);
    __half2 h0 = hz, h1 = hz, h2 = hz, h3 = hz;
    for (int j = 0; j < mp; j += 8) {
        int i0 = run[j + slot];
        int i1 = run[j + 4 + slot];
        float4 v0 = *(const float4*)(tbl + ((size_t)i0 << 4) + (hl << 3));
        float4 v1 = *(const float4*)(tbl + ((size_t)i1 << 4) + (hl << 3));
        const __half2* p0 = (const __half2*)&v0;
        const __half2* p1 = (const __half2*)&v1;
        h0 = __hadd2(h0, p0[0]); h1 = __hadd2(h1, p0[1]);
        h2 = __hadd2(h2, p0[2]); h3 = __hadd2(h3, p0[3]);
        h0 = __hadd2(h0, p1[0]); h1 = __hadd2(h1, p1[1]);
        h2 = __hadd2(h2, p1[2]); h3 = __hadd2(h3, p1[3]);
    }
    float2 f0 = __half22float2(h0);
    float2 f1 = __half22float2(h1);
    float2 f2 = __half22float2(h2);
    float2 f3 = __half22float2(h3);
    float a0 = f0.x, a1 = f0.y, a2 = f1.x, a3 = f1.y;
    float a4 = f2.x, a5 = f2.y, a6 = f3.x, a7 = f3.y;
    #pragma unroll
    for (int off = 2; off <= 4; off <<= 1) {
        a0 += __shfl_xor(a0, off);
        a1 += __shfl_xor(a1, off);
        a2 += __shfl_xor(a2, off);
        a3 += __shfl_xor(a3, off);
        a4 += __shfl_xor(a4, off);
        a5 += __shfl_xor(a5, off);
        a6 += __shfl_xor(a6, off);
        a7 += __shfl_xor(a7, off);
    }
    float dn = rsqrtf(fmaxf((float)m, 1.0f));
    if (slot == 0) {
        float* op = out + ((size_t)node << 6) + (pair << 4) + (hl << 3);
        *(float4*)(op) = make_float4(a0 * dn, a1 * dn, a2 * dn, a3 * dn);
        *(float4*)(op + 4) = make_float4(a4 * dn, a5 * dn, a6 * dn, a7 * dn);
    }
}

extern "C" void kernel_launch(void* const* d_in, const int* in_sizes, int n_in,
                              void* d_out, int out_size, void* d_ws, size_t ws_size,
                              hipStream_t stream) {
    const float* emb = (const float*)d_in[0];
    const int* src = (const int*)d_in[1];
    const int* dst = (const int*)d_in[2];
    int E = in_sizes[1];
    float* out = (float*)d_out;

    int* gcurD = (int*)d_ws;                                      // [NTPAD]
    int* gcurS = gcurD + NTPAD;                                   // [NTPAD]
    unsigned int* binnedD = (unsigned int*)(gcurS + NTPAD);       // [NTILES*CAP] ints
    int* sortedD = (int*)(binnedD + (size_t)NTILES * CAP);        // [NTILES*CAP] ints
    unsigned char* binnedSb = (unsigned char*)(sortedD + (size_t)NTILES * CAP); // [NTILES*CAP] bytes
    int* offs = (int*)(binnedSb + (size_t)NTILES * CAP);          // [N]
    int* deg = offs + NNODES;                                     // [N]
    __half* embp = (__half*)(deg + NNODES);                       // [NPAIR*(N+1)*16]

    init_kernel<<<(2 * NTPAD + 255) / 256, 256, 0, stream>>>(gcurD);

    int bin_blocks = (E + BIN_CHUNK - 1) / BIN_CHUNK;
    bin_kernel<<<bin_blocks, BIN_THREADS, 0, stream>>>(src, dst, gcurD, gcurS, binnedD, binnedSb, E);

    sortnorm_kernel<<<NTILES, SN_THREADS, 0, stream>>>(gcurS, binnedSb, gcurD, binnedD,
                                                       emb, embp, sortedD, offs, deg);

    int ngroups = (NNODES + 31) / 32;         // 3125
    agg6_kernel<<<ngroups * NPAIR, 256, 0, stream>>>(embp, offs, deg, sortedD, out);
}